// Round 4
// baseline (280.817 us; speedup 1.0000x reference)
//
#include <hip/hip_runtime.h>

// GRAPE axis-collapse: 20 X-rotations == one rotation by Theta = sum(a)*DT/2.
//   o0 = c*r0 + s*i1   o1 = c*r1 + s*i0   o2 = c*i0 - s*r1   o3 = c*i1 - s*r0
// R4: stream-split. Outputs pair as {o0,o3}<-(r0,i1) and {o1,o2}<-(r1,i0).
// Even blocks process pair A, odd blocks pair B -> each block touches only
// 2 read + 2 write linear streams (copy-like), and each thread handles 2
// ADJACENT float4s so a wave covers 2KB contiguous per stream per step.
// Same math both pairs: oa = c*x + s*y ; ob = c*y - s*x.

#define BLOCK 256

typedef float v4f __attribute__((ext_vector_type(4)));

__global__ __launch_bounds__(BLOCK) void grape_kernel(
    const float* __restrict__ amps, int nsteps,
    const v4f* __restrict__ sreal, const v4f* __restrict__ simag,
    v4f* __restrict__ out, long long B4) {
    // wave-uniform scalar prologue
    float theta = 0.0f;
    for (int k = 0; k < nsteps; ++k) theta += amps[k];
    theta *= 0.5f / (float)nsteps;  // DT/2, GATE_TIME = 1.0
    const float c = cosf(theta);
    const float s = sinf(theta);

    const int pair = blockIdx.x & 1;
    const long long pb = blockIdx.x >> 1;          // block index within pair
    const long long nb = gridDim.x >> 1;           // blocks per pair

    const v4f* __restrict__ xin;  // x stream
    const v4f* __restrict__ yin;  // y stream
    v4f* oa;
    v4f* ob;
    if (pair == 0) {
        xin = sreal;            // r0
        yin = simag + B4;       // i1
        oa  = out;              // o0 = c*r0 + s*i1
        ob  = out + 3 * B4;     // o3 = c*i1 - s*r0
    } else {
        xin = sreal + B4;       // r1
        yin = simag;            // i0
        oa  = out + B4;         // o1 = c*r1 + s*i0
        ob  = out + 2 * B4;     // o2 = c*i0 - s*r1
    }

    const long long stride = nb * (long long)BLOCK * 2;  // float4s per pair-iter
    for (long long j = (pb * BLOCK + threadIdx.x) * 2; j < B4; j += stride) {
        // two adjacent float4 per stream -> 2KB contiguous per wave per stream
        v4f x0 = xin[j];
        v4f x1 = (j + 1 < B4) ? xin[j + 1] : x0;
        v4f y0 = yin[j];
        v4f y1 = (j + 1 < B4) ? yin[j + 1] : y0;

        v4f a0 = c * x0 + s * y0;
        v4f a1 = c * x1 + s * y1;
        v4f b0 = c * y0 - s * x0;
        v4f b1 = c * y1 - s * x1;

        __builtin_nontemporal_store(a0, &oa[j]);
        __builtin_nontemporal_store(b0, &ob[j]);
        if (j + 1 < B4) {
            __builtin_nontemporal_store(a1, &oa[j + 1]);
            __builtin_nontemporal_store(b1, &ob[j + 1]);
        }
    }
}

extern "C" void kernel_launch(void* const* d_in, const int* in_sizes, int n_in,
                              void* d_out, int out_size, void* d_ws, size_t ws_size,
                              hipStream_t stream) {
    const float* amps  = (const float*)d_in[0];
    const float* sreal = (const float*)d_in[1];
    const float* simag = (const float*)d_in[2];
    float* out = (float*)d_out;

    int nsteps = in_sizes[0];
    long long B  = (long long)in_sizes[1] / 2;  // state_real is [2, B]
    long long B4 = B / 4;                       // float4 columns per row

    // blocks per pair sized so one iteration covers B4: nb*BLOCK*2 >= B4
    long long nb = (B4 + (long long)BLOCK * 2 - 1) / ((long long)BLOCK * 2);
    long long grid = 2 * nb;  // 8192 for B = 8388608

    grape_kernel<<<(dim3)(unsigned)grid, BLOCK, 0, stream>>>(
        amps, nsteps, (const v4f*)sreal, (const v4f*)simag,
        (v4f*)out, B4);
}

// Round 5
// 244.917 us; speedup vs baseline: 1.1466x; 1.1466x over previous
//
#include <hip/hip_runtime.h>

// GRAPE axis-collapse: 20 X-rotations == one rotation by Theta = sum(a)*DT/2.
// Decouples into two independent 2D systems:
//   A: (r0, i1) -> o0 = c*r0 + s*i1 ,  o3 = c*i1 - s*r0
//   B: (r1, i0) -> o1 = c*r1 + s*i0 ,  o2 = c*i0 - s*r1
// R5: even blocks run system A, odd blocks system B. Each block: 2 read + 2
// write streams, LANE-CONTIGUOUS float4 addressing (R4's 32B-stride store bug
// caused 2x write amplification), block-linear contiguous chunks for DRAM
// page / TLB locality.

#define BLOCK 256

typedef float v4f __attribute__((ext_vector_type(4)));

__global__ __launch_bounds__(BLOCK) void grape_kernel(
    const float* __restrict__ amps, int nsteps,
    const v4f* __restrict__ sreal, const v4f* __restrict__ simag,
    v4f* __restrict__ out, long long B4) {
    float theta = 0.0f;
    for (int k = 0; k < nsteps; ++k) theta += amps[k];
    theta *= 0.5f / (float)nsteps;  // DT/2, GATE_TIME = 1.0
    const float c = cosf(theta);
    const float s = sinf(theta);

    const int pair = blockIdx.x & 1;       // round-robin across XCDs
    const long long pb = blockIdx.x >> 1;  // block index within pair
    const long long nb = gridDim.x >> 1;   // blocks per pair

    const v4f* __restrict__ xin;
    const v4f* __restrict__ yin;
    v4f* oa;
    v4f* ob;
    if (pair == 0) {
        xin = sreal;           // r0
        yin = simag + B4;      // i1
        oa  = out;             // o0
        ob  = out + 3 * B4;    // o3
    } else {
        xin = sreal + B4;      // r1
        yin = simag;           // i0
        oa  = out + B4;        // o1
        ob  = out + 2 * B4;    // o2
    }

    // Block-linear contiguous chunk of the stream.
    const long long chunk = (B4 + nb - 1) / nb;
    const long long beg = pb * chunk;
    long long end = beg + chunk;
    if (end > B4) end = B4;

    for (long long j = beg + threadIdx.x; j < end; j += BLOCK) {
        v4f x = xin[j];
        v4f y = yin[j];
        v4f a = c * x + s * y;   // oa
        v4f b = c * y - s * x;   // ob
        __builtin_nontemporal_store(a, &oa[j]);
        __builtin_nontemporal_store(b, &ob[j]);
    }
}

extern "C" void kernel_launch(void* const* d_in, const int* in_sizes, int n_in,
                              void* d_out, int out_size, void* d_ws, size_t ws_size,
                              hipStream_t stream) {
    const float* amps  = (const float*)d_in[0];
    const float* sreal = (const float*)d_in[1];
    const float* simag = (const float*)d_in[2];
    float* out = (float*)d_out;

    int nsteps = in_sizes[0];
    long long B  = (long long)in_sizes[1] / 2;  // state_real is [2, B]
    long long B4 = B / 4;                       // float4 per row-stream

    // 2048 blocks: 1024 per system, chunk = 2048 float4 (32 KB/stream/block),
    // 8 iterations of 256 threads. 8 blocks/CU.
    long long grid = 2048;

    grape_kernel<<<(dim3)(unsigned)grid, BLOCK, 0, stream>>>(
        amps, nsteps, (const v4f*)sreal, (const v4f*)simag,
        (v4f*)out, B4);
}